// Round 12
// baseline (269.220 us; speedup 1.0000x reference)
//
#include <hip/hip_runtime.h>
#include <cstdint>
#include <cstddef>

#define N_ROWS 16384   // B*T
#define KCODES 4096
#define DIM    256

// -------- kernel 1: one WAVE per row — barrier-free scan + exact select --------
// Each wave holds its whole row (64 lanes x 16 float4 = 4096 u values) in
// VGPRs. Row gumbel-max via shfl reduce, threshold inverted once into u-space
// (margin 2.06 >= cos-spread 2 + inversion slop), register re-filter +
// ballot-ordered exact eval (elementwise-normalized fp32 dot, libm logf
// gumbel, first-index tie-break). No LDS, no __syncthreads, no cross-wave
// traffic; commitment via one atomicAdd per row.
__global__ __launch_bounds__(256) void row_kernel(
    const float* __restrict__ u, const float* __restrict__ z,
    const float* __restrict__ cb,
    float* __restrict__ zq, float* __restrict__ emb,
    float* __restrict__ idx_out, float* __restrict__ commit_acc)
{
    const int row  = blockIdx.x * 4 + (threadIdx.x >> 6);
    const int lane = threadIdx.x & 63;

    // ---- stream the whole u row into registers (16 x float4 per lane) ----
    const float4* ur4 = reinterpret_cast<const float4*>(u + (size_t)row * KCODES);
    float4 v[16];
    #pragma unroll
    for (int k = 0; k < 16; ++k) v[k] = ur4[k * 64 + lane];

    float4 zv = reinterpret_cast<const float4*>(z + (size_t)row * DIM)[lane];

    // ---- wave max of raw u (g monotone in u) ----
    float um = -1.0f;
    #pragma unroll
    for (int k = 0; k < 16; ++k)
        um = fmaxf(um, fmaxf(fmaxf(v[k].x, v[k].y), fmaxf(v[k].z, v[k].w)));
    #pragma unroll
    for (int m = 1; m <= 32; m <<= 1) um = fmaxf(um, __shfl_xor(um, m));

    // ---- z normalize (wave-local) ----
    float ss = zv.x*zv.x + zv.y*zv.y + zv.z*zv.z + zv.w*zv.w;
    #pragma unroll
    for (int m = 1; m <= 32; m <<= 1) ss += __shfl_xor(ss, m);
    const float zinv = 1.0f / fmaxf(sqrtf(ss), 1e-12f);
    float4 zn;
    zn.x = zv.x*zinv; zn.y = zv.y*zinv; zn.z = zv.z*zinv; zn.w = zv.w*zinv;

    // ---- invert threshold into u-space ----
    const float gmax  = -logf(-logf(um + 1e-10f) + 1e-10f);
    const float y_thr = expf(-(gmax - 2.06f)) - 1e-10f;
    float u_thr = expf(-y_thr) - 1e-10f;
    u_thr = u_thr - fabsf(u_thr) * 2e-6f - 1e-12f;   // few-ulp safety shrink

    // ---- register re-filter + ballot-ordered exact eval ----
    float best = -3.0e38f;
    int   bi   = 1 << 30;

    #pragma unroll
    for (int k = 0; k < 16; ++k) {
        float vv[4] = {v[k].x, v[k].y, v[k].z, v[k].w};
        #pragma unroll
        for (int e = 0; e < 4; ++e) {
            unsigned long long m = __ballot(vv[e] >= u_thr);
            while (m) {
                int src = __ffsll(m) - 1;
                m &= m - 1;
                float uu  = __shfl(vv[e], src);
                // v[k] = ur4[k*64 + lane] -> element col:
                int   col = k * 256 + src * 4 + e;
                float4 cv = reinterpret_cast<const float4*>(cb + (size_t)col * DIM)[lane];
                float sc = cv.x*cv.x + cv.y*cv.y + cv.z*cv.z + cv.w*cv.w;
                #pragma unroll
                for (int mm = 1; mm <= 32; mm <<= 1) sc += __shfl_xor(sc, mm);
                float civ = 1.0f / fmaxf(sqrtf(sc), 1e-12f);
                float d = zn.x*(cv.x*civ) + zn.y*(cv.y*civ) + zn.z*(cv.z*civ) + zn.w*(cv.w*civ);
                #pragma unroll
                for (int mm = 1; mm <= 32; mm <<= 1) d += __shfl_xor(d, mm);
                float y1 = -logf(uu + 1e-10f);
                float g  = -logf(y1 + 1e-10f);
                float val = (d - 1.0f) + g;
                if (val > best || (val == best && col < bi)) { best = val; bi = col; }
            }
        }
    }

    // ---- winner gather + outputs (wave-private) ----
    float4 cw = reinterpret_cast<const float4*>(cb + (size_t)bi * DIM)[lane];
    reinterpret_cast<float4*>(zq  + (size_t)row * DIM)[lane] = cw;
    reinterpret_cast<float4*>(emb + (size_t)row * DIM)[lane] = cw;
    float dx = cw.x - zv.x, dy = cw.y - zv.y, dz = cw.z - zv.z, dw = cw.w - zv.w;
    float s2 = dx*dx + dy*dy + dz*dz + dw*dw;
    #pragma unroll
    for (int m = 1; m <= 32; m <<= 1) s2 += __shfl_xor(s2, m);
    if (lane == 0) {
        idx_out[row] = (float)bi;
        atomicAdd(commit_acc, s2);
    }
}

// -------- kernel 2: scalars (commitment, entropy bonus, perplexity, entropy) --------
__global__ __launch_bounds__(256) void scalars_kernel(
    const float* __restrict__ commit_acc, const float* __restrict__ usage,
    const int* __restrict__ step_ptr, float* __restrict__ out4)
{
    __shared__ float red[256];
    int t = threadIdx.x;

    float us = 0.f;
    for (int i = t; i < KCODES; i += 256) us += usage[i];
    red[t] = us; __syncthreads();
    for (int w = 128; w > 0; w >>= 1) { if (t < w) red[t] += red[t + w]; __syncthreads(); }
    float usage_sum = red[0];
    __syncthreads();

    float e = 0.f;
    for (int i = t; i < KCODES; i += 256) {
        float p = (usage_sum > 0.f) ? usage[i] / (usage_sum + 1e-10f) : (1.0f / KCODES);
        e += p * logf(p + 1e-10f);
    }
    red[t] = e; __syncthreads();
    for (int w = 128; w > 0; w >>= 1) { if (t < w) red[t] += red[t + w]; __syncthreads(); }

    if (t == 0) {
        float entropy = -red[0];
        int step_after = step_ptr[0] + 1;
        float bonus_w = 0.05f * (1.0f - (float)step_after / 20000.0f);
        float eb = (step_after < 20000) ? (-bonus_w * entropy) : 0.0f;
        out4[0] = 0.5f * commit_acc[0] / 4194304.0f;
        out4[1] = eb;
        out4[2] = expf(entropy);
        out4[3] = entropy;
    }
}

extern "C" void kernel_launch(void* const* d_in, const int* in_sizes, int n_in,
                              void* d_out, int out_size, void* d_ws, size_t ws_size,
                              hipStream_t stream)
{
    const float* z     = (const float*)d_in[0];   // [16,1024,256]
    const float* u     = (const float*)d_in[1];   // [16,1024,4096]
    const float* cb    = (const float*)d_in[2];   // [4096,256]
    const float* usage = (const float*)d_in[3];   // [4096]
    const int*   step  = (const int*)d_in[4];     // scalar

    float* out  = (float*)d_out;
    float* zq   = out;                 // 4194304
    float* emb  = out + 4194304;       // 4194304
    float* idxo = out + 8388608;       // 16384
    float* scal = out + 8404992;       // 4

    float* commit_acc = (float*)d_ws;  // single accumulator

    hipMemsetAsync(commit_acc, 0, sizeof(float), stream);
    hipLaunchKernelGGL(row_kernel, dim3(N_ROWS / 4), dim3(256), 0, stream,
                       u, z, cb, zq, emb, idxo, commit_acc);
    hipLaunchKernelGGL(scalars_kernel, dim3(1), dim3(256), 0, stream,
                       commit_acc, usage, step, scal);
}

// Round 13
// 249.753 us; speedup vs baseline: 1.0779x; 1.0779x over previous
//
#include <hip/hip_runtime.h>
#include <cstdint>
#include <cstddef>

#define N_ROWS 16384   // B*T
#define KCODES 4096
#define DIM    256

// -------- kernel 1: fused per-row scan + exact select + gather --------
// One block (4 waves) per row — the R10-verified structure (v[4]=16 regs per
// thread stays live; bigger register arrays trigger compiler remat, R11/R12).
// Phase 1: block-max of RAW u (g monotone in u), threshold inverted once into
// u-space (margin 2.06 >= cos-spread 2 + inversion slop). Phase 2: ballot
// re-filter + wave-split exact eval (elementwise-normalized fp32 dot, libm
// logf gumbel, first-index tie-break). Commitment via one atomicAdd per row.
__global__ __launch_bounds__(256, 8) void row_kernel(
    const float* __restrict__ u, const float* __restrict__ z,
    const float* __restrict__ cb,
    float* __restrict__ zq, float* __restrict__ emb,
    float* __restrict__ idx_out, float* __restrict__ commit_acc)
{
    const int row  = blockIdx.x;
    const int t    = threadIdx.x, lane = t & 63, wave = t >> 6;

    __shared__ float s_max[4];
    __shared__ float s_bestv[4];
    __shared__ int   s_besti[4];

    // ---- phase 1: stream u row (16 floats/thread), z row per wave ----
    const float4* ur4 = reinterpret_cast<const float4*>(u + (size_t)row * KCODES);
    float4 v[4];
    #pragma unroll
    for (int k = 0; k < 4; ++k) v[k] = ur4[k * 256 + t];

    float4 zv = reinterpret_cast<const float4*>(z + (size_t)row * DIM)[lane];

    float um = -1.0f;
    #pragma unroll
    for (int k = 0; k < 4; ++k)
        um = fmaxf(um, fmaxf(fmaxf(v[k].x, v[k].y), fmaxf(v[k].z, v[k].w)));
    #pragma unroll
    for (int m = 1; m <= 32; m <<= 1) um = fmaxf(um, __shfl_xor(um, m));
    if (lane == 0) s_max[wave] = um;

    // z normalize (per wave, overlaps with other waves' maxes)
    float ss = zv.x*zv.x + zv.y*zv.y + zv.z*zv.z + zv.w*zv.w;
    #pragma unroll
    for (int m = 1; m <= 32; m <<= 1) ss += __shfl_xor(ss, m);
    const float zinv = 1.0f / fmaxf(sqrtf(ss), 1e-12f);
    float4 zn;
    zn.x = zv.x*zinv; zn.y = zv.y*zinv; zn.z = zv.z*zinv; zn.w = zv.w*zinv;

    __syncthreads();
    const float umax = fmaxf(fmaxf(s_max[0], s_max[1]), fmaxf(s_max[2], s_max[3]));

    // invert threshold into u-space: g(u) = -log(-log(u+1e-10)+1e-10) is
    // monotone non-decreasing in u even in float (rounded monotone ops).
    const float gmax  = -logf(-logf(umax + 1e-10f) + 1e-10f);
    const float y_thr = expf(-(gmax - 2.06f)) - 1e-10f;
    float u_thr = expf(-y_thr) - 1e-10f;
    u_thr = u_thr - fabsf(u_thr) * 2e-6f - 1e-12f;   // few-ulp safety shrink

    // ---- phase 2: wave-local ballot eval of threshold hits ----
    float best = -3.0e38f;
    int   bi   = 1 << 30;

    #pragma unroll
    for (int k = 0; k < 4; ++k) {
        float vv[4] = {v[k].x, v[k].y, v[k].z, v[k].w};
        #pragma unroll
        for (int e = 0; e < 4; ++e) {
            unsigned long long m = __ballot(vv[e] >= u_thr);
            while (m) {
                int src = __ffsll(m) - 1;
                m &= m - 1;
                float uu  = __shfl(vv[e], src);
                // load was ur4[k*256 + wave*64 + lane] -> element col:
                int   col = k * 1024 + wave * 256 + src * 4 + e;
                float4 cv = reinterpret_cast<const float4*>(cb + (size_t)col * DIM)[lane];
                float sc = cv.x*cv.x + cv.y*cv.y + cv.z*cv.z + cv.w*cv.w;
                #pragma unroll
                for (int mm = 1; mm <= 32; mm <<= 1) sc += __shfl_xor(sc, mm);
                float civ = 1.0f / fmaxf(sqrtf(sc), 1e-12f);
                float d = zn.x*(cv.x*civ) + zn.y*(cv.y*civ) + zn.z*(cv.z*civ) + zn.w*(cv.w*civ);
                #pragma unroll
                for (int mm = 1; mm <= 32; mm <<= 1) d += __shfl_xor(d, mm);
                float y1 = -logf(uu + 1e-10f);
                float g  = -logf(y1 + 1e-10f);
                float val = (d - 1.0f) + g;
                if (val > best || (val == best && col < bi)) { best = val; bi = col; }
            }
        }
    }
    if (lane == 0) { s_bestv[wave] = best; s_besti[wave] = bi; }
    __syncthreads();

    // ---- phase 3: combine; wave0 -> zq+idx+commit, wave1 -> emb ----
    best = s_bestv[0]; bi = s_besti[0];
    #pragma unroll
    for (int w = 1; w < 4; ++w) {
        float ov = s_bestv[w]; int oi = s_besti[w];
        if (ov > best || (ov == best && oi < bi)) { best = ov; bi = oi; }
    }
    if (wave == 0) {
        float4 cw = reinterpret_cast<const float4*>(cb + (size_t)bi * DIM)[lane];
        reinterpret_cast<float4*>(zq + (size_t)row * DIM)[lane] = cw;
        float dx = cw.x - zv.x, dy = cw.y - zv.y, dz = cw.z - zv.z, dw = cw.w - zv.w;
        float s2 = dx*dx + dy*dy + dz*dz + dw*dw;
        #pragma unroll
        for (int m = 1; m <= 32; m <<= 1) s2 += __shfl_xor(s2, m);
        if (lane == 0) {
            idx_out[row] = (float)bi;
            atomicAdd(commit_acc, s2);
        }
    } else if (wave == 1) {
        float4 cw = reinterpret_cast<const float4*>(cb + (size_t)bi * DIM)[lane];
        reinterpret_cast<float4*>(emb + (size_t)row * DIM)[lane] = cw;
    }
}

// -------- kernel 2: scalars (commitment, entropy bonus, perplexity, entropy) --------
__global__ __launch_bounds__(256) void scalars_kernel(
    const float* __restrict__ commit_acc, const float* __restrict__ usage,
    const int* __restrict__ step_ptr, float* __restrict__ out4)
{
    __shared__ float red[256];
    int t = threadIdx.x;

    float us = 0.f;
    for (int i = t; i < KCODES; i += 256) us += usage[i];
    red[t] = us; __syncthreads();
    for (int w = 128; w > 0; w >>= 1) { if (t < w) red[t] += red[t + w]; __syncthreads(); }
    float usage_sum = red[0];
    __syncthreads();

    float e = 0.f;
    for (int i = t; i < KCODES; i += 256) {
        float p = (usage_sum > 0.f) ? usage[i] / (usage_sum + 1e-10f) : (1.0f / KCODES);
        e += p * logf(p + 1e-10f);
    }
    red[t] = e; __syncthreads();
    for (int w = 128; w > 0; w >>= 1) { if (t < w) red[t] += red[t + w]; __syncthreads(); }

    if (t == 0) {
        float entropy = -red[0];
        int step_after = step_ptr[0] + 1;
        float bonus_w = 0.05f * (1.0f - (float)step_after / 20000.0f);
        float eb = (step_after < 20000) ? (-bonus_w * entropy) : 0.0f;
        out4[0] = 0.5f * commit_acc[0] / 4194304.0f;
        out4[1] = eb;
        out4[2] = expf(entropy);
        out4[3] = entropy;
    }
}

extern "C" void kernel_launch(void* const* d_in, const int* in_sizes, int n_in,
                              void* d_out, int out_size, void* d_ws, size_t ws_size,
                              hipStream_t stream)
{
    const float* z     = (const float*)d_in[0];   // [16,1024,256]
    const float* u     = (const float*)d_in[1];   // [16,1024,4096]
    const float* cb    = (const float*)d_in[2];   // [4096,256]
    const float* usage = (const float*)d_in[3];   // [4096]
    const int*   step  = (const int*)d_in[4];     // scalar

    float* out  = (float*)d_out;
    float* zq   = out;                 // 4194304
    float* emb  = out + 4194304;       // 4194304
    float* idxo = out + 8388608;       // 16384
    float* scal = out + 8404992;       // 4

    float* commit_acc = (float*)d_ws;  // single accumulator

    hipMemsetAsync(commit_acc, 0, sizeof(float), stream);
    hipLaunchKernelGGL(row_kernel, dim3(N_ROWS), dim3(256), 0, stream,
                       u, z, cb, zq, emb, idxo, commit_acc);
    hipLaunchKernelGGL(scalars_kernel, dim3(1), dim3(256), 0, stream,
                       commit_acc, usage, step, scal);
}

// Round 14
// 95.364 us; speedup vs baseline: 2.8231x; 2.6189x over previous
//
#include <hip/hip_runtime.h>
#include <cstdint>
#include <cstddef>

#define N_ROWS 16384   // B*T
#define KCODES 4096
#define DIM    256
#define CAP    128     // geometric tail, mean ~7.8: P(row overflow) ~ 1e-7

// -------- kernel 1: codebook inverse norms --------
__global__ __launch_bounds__(256) void cinv_kernel(
    const float* __restrict__ cb, float* __restrict__ cinv)
{
    int r    = blockIdx.x * 4 + (threadIdx.x >> 6);   // one wave per codebook row
    int lane = threadIdx.x & 63;
    float4 v = reinterpret_cast<const float4*>(cb + (size_t)r * DIM)[lane];
    float s = v.x*v.x + v.y*v.y + v.z*v.z + v.w*v.w;
    #pragma unroll
    for (int m = 1; m <= 32; m <<= 1) s += __shfl_xor(s, m);
    if (lane == 0) cinv[r] = 1.0f / fmaxf(sqrtf(s), 1e-12f);
}

// -------- kernel 2: fused per-row scan + exact select + gather --------
// BYTE-IDENTICAL to the R8-verified kernel (106.3 us): any perturbation of
// this body risks the hipcc remat regression seen in R11/R12/R13.
__global__ __launch_bounds__(256) void row_kernel(
    const float* __restrict__ u, const float* __restrict__ z,
    const float* __restrict__ cb, const float* __restrict__ cinv,
    float* __restrict__ zq, float* __restrict__ emb,
    float* __restrict__ idx_out, float* __restrict__ commit_part)
{
    const int row  = blockIdx.x;
    const int t    = threadIdx.x, lane = t & 63, wave = t >> 6;

    __shared__ float2 cand[CAP];
    __shared__ int    s_cnt;
    __shared__ float  s_max[4];
    __shared__ float  s_bestv[4];
    __shared__ int    s_besti[4];

    if (t == 0) s_cnt = 0;

    // ---- phase 1: stream u row, block umax, u-space threshold, collect ----
    const float4* ur4 = reinterpret_cast<const float4*>(u + (size_t)row * KCODES);
    float4 v[4];
    #pragma unroll
    for (int k = 0; k < 4; ++k) v[k] = ur4[k * 256 + t];

    float um = -1.0f;
    #pragma unroll
    for (int k = 0; k < 4; ++k)
        um = fmaxf(um, fmaxf(fmaxf(v[k].x, v[k].y), fmaxf(v[k].z, v[k].w)));
    #pragma unroll
    for (int m = 1; m <= 32; m <<= 1) um = fmaxf(um, __shfl_xor(um, m));
    if (lane == 0) s_max[wave] = um;
    __syncthreads();
    const float umax = fmaxf(fmaxf(s_max[0], s_max[1]), fmaxf(s_max[2], s_max[3]));

    // invert: g(u) = -log(-log(u+1e-10)+1e-10) monotone in u.
    // winner needs g >= gmax - 2 (cos-spread <= 2); margin 2.06 + ulp shrink.
    const float gmax  = -logf(-logf(umax + 1e-10f) + 1e-10f);
    const float y_thr = expf(-(gmax - 2.06f)) - 1e-10f;
    float u_thr = expf(-y_thr) - 1e-10f;
    u_thr = u_thr - fabsf(u_thr) * 2e-6f - 1e-12f;   // few-ulp safety shrink

    #pragma unroll
    for (int k = 0; k < 4; ++k) {
        float vv[4] = {v[k].x, v[k].y, v[k].z, v[k].w};
        #pragma unroll
        for (int e = 0; e < 4; ++e) {
            if (vv[e] >= u_thr) {
                int pos = atomicAdd(&s_cnt, 1);
                if (pos < CAP)
                    cand[pos] = make_float2(vv[e], (float)((k * 256 + t) * 4 + e));
            }
        }
    }
    __syncthreads();
    const int n = s_cnt;

    // ---- phase 2: z normalize (per wave), candidate eval split across waves ----
    float4 zv = reinterpret_cast<const float4*>(z + (size_t)row * DIM)[lane];
    float ss = zv.x*zv.x + zv.y*zv.y + zv.z*zv.z + zv.w*zv.w;
    #pragma unroll
    for (int m = 1; m <= 32; m <<= 1) ss += __shfl_xor(ss, m);
    const float zinv = 1.0f / fmaxf(sqrtf(ss), 1e-12f);
    float4 zn;
    zn.x = zv.x*zinv; zn.y = zv.y*zinv; zn.z = zv.z*zinv; zn.w = zv.w*zinv;

    float best = -3.0e38f;
    int   bi   = 1 << 30;

    auto evalc = [&](float uu, int col) {
        float4 cv = reinterpret_cast<const float4*>(cb + (size_t)col * DIM)[lane];
        float civ = cinv[col];
        float d = zn.x*(cv.x*civ) + zn.y*(cv.y*civ) + zn.z*(cv.z*civ) + zn.w*(cv.w*civ);
        #pragma unroll
        for (int m = 1; m <= 32; m <<= 1) d += __shfl_xor(d, m);
        float y1 = -logf(uu + 1e-10f);
        float g  = -logf(y1 + 1e-10f);
        float val = (d - 1.0f) + g;
        if (val > best || (val == best && col < bi)) { best = val; bi = col; }
    };

    if (n <= CAP) {
        for (int c = wave; c < n; c += 4) {
            float2 cd = cand[c];
            evalc(cd.x, (int)cd.y);
        }
    } else {
        // exact full-row fallback, wave-parallel (effectively never taken)
        const float* urow = u + (size_t)row * KCODES;
        for (int col = wave; col < KCODES; col += 4) evalc(urow[col], col);
    }
    if (lane == 0) { s_bestv[wave] = best; s_besti[wave] = bi; }
    __syncthreads();

    // ---- phase 3: all waves combine; wave0 -> zq+commit, wave1 -> emb ----
    best = s_bestv[0]; bi = s_besti[0];
    #pragma unroll
    for (int w = 1; w < 4; ++w) {
        float ov = s_bestv[w]; int oi = s_besti[w];
        if (ov > best || (ov == best && oi < bi)) { best = ov; bi = oi; }
    }
    if (wave == 0) {
        float4 cw = reinterpret_cast<const float4*>(cb + (size_t)bi * DIM)[lane];
        reinterpret_cast<float4*>(zq + (size_t)row * DIM)[lane] = cw;
        float dx = cw.x - zv.x, dy = cw.y - zv.y, dz = cw.z - zv.z, dw = cw.w - zv.w;
        float s2 = dx*dx + dy*dy + dz*dz + dw*dw;
        #pragma unroll
        for (int m = 1; m <= 32; m <<= 1) s2 += __shfl_xor(s2, m);
        if (lane == 0) {
            idx_out[row]     = (float)bi;
            commit_part[row] = s2;
        }
    } else if (wave == 1) {
        float4 cw = reinterpret_cast<const float4*>(cb + (size_t)bi * DIM)[lane];
        reinterpret_cast<float4*>(emb + (size_t)row * DIM)[lane] = cw;
    }
}

// -------- kernel 3: parallel commit reduction (16 blocks, float4 loads) --------
__global__ __launch_bounds__(256) void commit_reduce_kernel(
    const float* __restrict__ commit_part, float* __restrict__ commit_acc)
{
    __shared__ float red[256];
    const int t = threadIdx.x;
    float4 v = reinterpret_cast<const float4*>(commit_part)[blockIdx.x * 256 + t];
    red[t] = v.x + v.y + v.z + v.w;
    __syncthreads();
    for (int w = 128; w > 0; w >>= 1) { if (t < w) red[t] += red[t + w]; __syncthreads(); }
    if (t == 0) atomicAdd(commit_acc, red[0]);
}

// -------- kernel 4: scalars (commitment, entropy bonus, perplexity, entropy) --------
__global__ __launch_bounds__(256) void scalars_kernel(
    const float* __restrict__ commit_acc, const float* __restrict__ usage,
    const int* __restrict__ step_ptr, float* __restrict__ out4)
{
    __shared__ float red[256];
    int t = threadIdx.x;

    float us = 0.f;
    for (int i = t; i < KCODES; i += 256) us += usage[i];
    red[t] = us; __syncthreads();
    for (int w = 128; w > 0; w >>= 1) { if (t < w) red[t] += red[t + w]; __syncthreads(); }
    float usage_sum = red[0];
    __syncthreads();

    float e = 0.f;
    for (int i = t; i < KCODES; i += 256) {
        float p = (usage_sum > 0.f) ? usage[i] / (usage_sum + 1e-10f) : (1.0f / KCODES);
        e += p * logf(p + 1e-10f);
    }
    red[t] = e; __syncthreads();
    for (int w = 128; w > 0; w >>= 1) { if (t < w) red[t] += red[t + w]; __syncthreads(); }

    if (t == 0) {
        float entropy = -red[0];
        int step_after = step_ptr[0] + 1;
        float bonus_w = 0.05f * (1.0f - (float)step_after / 20000.0f);
        float eb = (step_after < 20000) ? (-bonus_w * entropy) : 0.0f;
        out4[0] = 0.5f * commit_acc[0] / 4194304.0f;
        out4[1] = eb;
        out4[2] = expf(entropy);
        out4[3] = entropy;
    }
}

extern "C" void kernel_launch(void* const* d_in, const int* in_sizes, int n_in,
                              void* d_out, int out_size, void* d_ws, size_t ws_size,
                              hipStream_t stream)
{
    const float* z     = (const float*)d_in[0];   // [16,1024,256]
    const float* u     = (const float*)d_in[1];   // [16,1024,4096]
    const float* cb    = (const float*)d_in[2];   // [4096,256]
    const float* usage = (const float*)d_in[3];   // [4096]
    const int*   step  = (const int*)d_in[4];     // scalar

    float* out  = (float*)d_out;
    float* zq   = out;                 // 4194304
    float* emb  = out + 4194304;       // 4194304
    float* idxo = out + 8388608;       // 16384
    float* scal = out + 8404992;       // 4

    float* ws          = (float*)d_ws;
    float* cinv        = ws;           // 4096
    float* commit_part = ws + 4096;    // 16384
    float* commit_acc  = ws + 20480;   // 1

    hipMemsetAsync(commit_acc, 0, sizeof(float), stream);
    hipLaunchKernelGGL(cinv_kernel, dim3(1024), dim3(256), 0, stream, cb, cinv);
    hipLaunchKernelGGL(row_kernel, dim3(N_ROWS), dim3(256), 0, stream,
                       u, z, cb, cinv, zq, emb, idxo, commit_part);
    hipLaunchKernelGGL(commit_reduce_kernel, dim3(16), dim3(256), 0, stream,
                       commit_part, commit_acc);
    hipLaunchKernelGGL(scalars_kernel, dim3(1), dim3(256), 0, stream,
                       commit_acc, usage, step, scal);
}